// Round 4
// baseline (1063.269 us; speedup 1.0000x reference)
//
#include <hip/hip_runtime.h>

typedef __bf16 bf16x8 __attribute__((ext_vector_type(8)));
typedef short short8_t __attribute__((ext_vector_type(8)));
typedef float f32x4 __attribute__((ext_vector_type(4)));
typedef unsigned short us4_t __attribute__((ext_vector_type(4)));

#define SCALE 0.08838834764831845f  // 1/sqrt(128)

__device__ __forceinline__ float b2f(unsigned short u) {
  union { unsigned int i; float f; } v; v.i = ((unsigned int)u) << 16; return v.f;
}
__device__ __forceinline__ unsigned short f2b(float f) {
  union { float f; unsigned int i; } v; v.f = f;
  unsigned int r = v.i + 0x7fffu + ((v.i >> 16) & 1u);
  return (unsigned short)(r >> 16);
}

__device__ __forceinline__ f32x4 mfma16(short8_t a, short8_t b, f32x4 c) {
  return __builtin_amdgcn_mfma_f32_16x16x32_bf16(
      __builtin_bit_cast(bf16x8, a), __builtin_bit_cast(bf16x8, b), c, 0, 0, 0);
}

typedef __attribute__((address_space(1))) const void gas_t;
typedef __attribute__((address_space(3))) void las_t;
__device__ __forceinline__ void gload16(const void* g, void* l) {
  __builtin_amdgcn_global_load_lds((gas_t*)g, (las_t*)l, 16, 0, 0);
}

// ---------------- fp32 -> bf16 convert ----------------
__global__ void cvt_kernel(const float* __restrict__ src, unsigned short* __restrict__ dst, int n4) {
  for (int i = blockIdx.x * blockDim.x + threadIdx.x; i < n4; i += gridDim.x * blockDim.x) {
    f32x4 v = *(const f32x4*)(src + (size_t)i * 4);
    us4_t o;
    o[0] = f2b(v[0]); o[1] = f2b(v[1]); o[2] = f2b(v[2]); o[3] = f2b(v[3]);
    *(us4_t*)(dst + (size_t)i * 4) = o;
  }
}

// ---------------- 128x128 bf16 GEMM core (C = A * Bt^T) ----------------
// MODE: 0 = f32 out, 1 = bf16 out, 2 = bf16 transposed-V out
//   mode 2: Cout is xvT; element (row,col) stored at
//           xvT[((row>>11)*1024 + col)*2048 + (row&2047)]   (col = global n index)
template <int MODE>
__device__ __forceinline__ void gemm128(const unsigned short* __restrict__ A,
                                        const unsigned short* __restrict__ Bt,
                                        void* __restrict__ Cout,
                                        int m0, int n0, int K, int ldc) {
  __shared__ __align__(16) unsigned short As[128 * 32];
  __shared__ __align__(16) unsigned short Bs[128 * 32];
  const int tid = threadIdx.x;
  const int wave = tid >> 6, lane = tid & 63;
  const int ln = lane & 15, g = lane >> 4;
  const int wm = (wave >> 1) * 64, wn = (wave & 1) * 64;

  const int rA0 = wave * 16 + (lane >> 2);
  const int rA1 = 64 + wave * 16 + (lane >> 2);
  const int colx = (lane & 3) * 8;
  const unsigned short* gA0 = A + (size_t)(m0 + rA0) * K + colx;
  const unsigned short* gA1 = A + (size_t)(m0 + rA1) * K + colx;
  const unsigned short* gB0 = Bt + (size_t)(n0 + rA0) * K + colx;
  const unsigned short* gB1 = Bt + (size_t)(n0 + rA1) * K + colx;
  unsigned short* lA0 = As + wave * 512;
  unsigned short* lA1 = As + 2048 + wave * 512;
  unsigned short* lB0 = Bs + wave * 512;
  unsigned short* lB1 = Bs + 2048 + wave * 512;

  f32x4 acc[4][4] = {};

  for (int k0 = 0; k0 < K; k0 += 32) {
    gload16(gA0 + k0, lA0);
    gload16(gA1 + k0, lA1);
    gload16(gB0 + k0, lB0);
    gload16(gB1 + k0, lB1);
    __syncthreads();
    short8_t a[4], b[4];
#pragma unroll
    for (int i = 0; i < 4; ++i)
      a[i] = *(const short8_t*)(As + (wm + i * 16 + ln) * 32 + g * 8);
#pragma unroll
    for (int j = 0; j < 4; ++j)
      b[j] = *(const short8_t*)(Bs + (wn + j * 16 + ln) * 32 + g * 8);
#pragma unroll
    for (int i = 0; i < 4; ++i)
#pragma unroll
      for (int j = 0; j < 4; ++j)
        acc[i][j] = mfma16(a[i], b[j], acc[i][j]);
    __syncthreads();
  }

#pragma unroll
  for (int i = 0; i < 4; ++i) {
#pragma unroll
    for (int j = 0; j < 4; ++j) {
      if (MODE == 2) {
        // transposed V store: 4 consecutive s (rows) for one col -> one b64
        int row0 = m0 + wm + i * 16 + g * 4;
        int col = n0 + wn + j * 16 + ln;
        us4_t pk;
#pragma unroll
        for (int r = 0; r < 4; ++r) pk[r] = f2b(acc[i][j][r]);
        *(us4_t*)((unsigned short*)Cout +
                  ((size_t)((row0 >> 11) * 1024 + col)) * 2048 + (row0 & 2047)) = pk;
      } else {
#pragma unroll
        for (int r = 0; r < 4; ++r) {
          int row = m0 + wm + i * 16 + g * 4 + r;
          int col = n0 + wn + j * 16 + ln;
          if (MODE == 1)
            ((unsigned short*)Cout)[(size_t)row * ldc + col] = f2b(acc[i][j][r]);
          else
            ((float*)Cout)[(size_t)row * ldc + col] = acc[i][j][r];
        }
      }
    }
  }
}

__global__ __launch_bounds__(256) void gemm_qkv_kernel(
    const unsigned short* __restrict__ xb, const unsigned short* __restrict__ wqb,
    const unsigned short* __restrict__ wkb, const unsigned short* __restrict__ wvb,
    unsigned short* __restrict__ xq, unsigned short* __restrict__ xk,
    unsigned short* __restrict__ xvT) {
  int bx = blockIdx.x, by = blockIdx.y;
  if (bx < 32)      gemm128<1>(xb, wqb, xq, by * 128, bx * 128, 4096, 4096);
  else if (bx < 40) gemm128<1>(xb, wkb, xk, by * 128, (bx - 32) * 128, 4096, 1024);
  else              gemm128<2>(xb, wvb, xvT, by * 128, (bx - 40) * 128, 4096, 0);
}

__global__ __launch_bounds__(256) void gemm_o_kernel(
    const unsigned short* __restrict__ ao, const unsigned short* __restrict__ wob,
    float* __restrict__ out) {
  gemm128<0>(ao, wob, out, blockIdx.y * 128, blockIdx.x * 128, 4096, 4096);
}

// ---------------- RoPE ----------------
template <int NH>
__global__ void rope_kernel(unsigned short* __restrict__ p, const float* __restrict__ fr,
                            int nchunks) {
  for (int c = blockIdx.x * blockDim.x + threadIdx.x; c < nchunks;
       c += gridDim.x * blockDim.x) {
    size_t e = (size_t)c * 8;
    int f0 = (c & 15) * 4;
    int rest = (int)(e >> 7);
    int s = (rest / NH) & 2047;
    unsigned short* ptr = p + e;
    short8_t v = *(short8_t*)ptr;
    const float* cosp = fr + (size_t)s * 64 + f0;
    const float* sinp = cosp + 131072;
#pragma unroll
    for (int j = 0; j < 4; ++j) {
      float re = b2f((unsigned short)v[2 * j]);
      float im = b2f((unsigned short)v[2 * j + 1]);
      float cc = cosp[j], ss = sinp[j];
      v[2 * j]     = (short)f2b(re * cc - im * ss);
      v[2 * j + 1] = (short)f2b(re * ss + im * cc);
    }
    *(short8_t*)ptr = v;
  }
}

// ---------------- flash attention (Round-1 verified structure) ----------------
// grid (32 qtiles, 32 heads, 2 batch), 256 threads (4 waves x 16 q-rows)
// V is consumed pre-transposed (xvT) -> staged like K, no in-kernel transpose.
__global__ __launch_bounds__(256) void attn_kernel(
    const unsigned short* __restrict__ xq, const unsigned short* __restrict__ xk,
    const unsigned short* __restrict__ xvT, unsigned short* __restrict__ ao) {
  __shared__ __align__(16) unsigned short Klds[64 * 136];  // padded stride 136
  __shared__ __align__(16) unsigned short VT[128 * 72];    // V^T, padded stride 72
  __shared__ __align__(16) unsigned short Plds[4 * 16 * 72];

  const int tid = threadIdx.x;
  const int wave = tid >> 6, lane = tid & 63;
  const int ln = lane & 15, g = lane >> 4;
  const int bx = 31 - blockIdx.x;            // LPT: heaviest tiles dispatch first
  const int h = blockIdx.y, b = blockIdx.z;
  const int hkv = h >> 2;
  const int q0 = bx * 64;

  // Q fragments in registers
  const unsigned short* qb = xq + ((size_t)(b * 2048 + q0 + wave * 16 + ln) * 32 + h) * 128;
  short8_t qf[4];
#pragma unroll
  for (int s = 0; s < 4; ++s) qf[s] = *(const short8_t*)(qb + s * 32 + g * 8);

  f32x4 acc_o[8] = {};
  float m_run[4] = {-1e30f, -1e30f, -1e30f, -1e30f};
  float l_run[4] = {0.f, 0.f, 0.f, 0.f};

  const unsigned short* kbase = xk + ((size_t)(b * 2048) * 8 + hkv) * 128;
  const unsigned short* vtg = xvT + (size_t)(b * 1024 + hkv * 128) * 2048;  // rows d, 2048 s
  unsigned short* pw = Plds + wave * 16 * 72;

  for (int kt = 0; kt <= bx; ++kt) {
    const int ks = kt * 64;
    const bool diag = (kt == bx);
    __syncthreads();  // previous tile's LDS reads done
    // stage K tile [64 k][128 d] -> Klds padded stride 136
#pragma unroll
    for (int i = 0; i < 4; ++i) {
      int cid = i * 256 + tid;
      int r = cid >> 4, cc = cid & 15;
      short8_t kv = *(const short8_t*)(kbase + (size_t)(ks + r) * 1024 + cc * 8);
      *(short8_t*)(Klds + r * 136 + cc * 8) = kv;
    }
    // stage V^T tile [128 d][64 k] from xvT -> VT stride 72 (b128 in, b128 out)
#pragma unroll
    for (int i = 0; i < 4; ++i) {
      int idx = i * 256 + tid;
      int d = idx >> 3, kb = idx & 7;
      short8_t vv = *(const short8_t*)(vtg + (size_t)d * 2048 + ks + kb * 8);
      *(short8_t*)(VT + d * 72 + kb * 8) = vv;
    }
    __syncthreads();

    // QK^T: scores S[16 q][64 k] per wave
    f32x4 sc[4] = {};
#pragma unroll
    for (int s = 0; s < 4; ++s) {
#pragma unroll
      for (int kb = 0; kb < 4; ++kb) {
        short8_t kf = *(const short8_t*)(Klds + (kb * 16 + ln) * 136 + s * 32 + g * 8);
        sc[kb] = mfma16(qf[s], kf, sc[kb]);
      }
    }
    // scale + causal mask
    const int rowg = q0 + wave * 16 + g * 4;
#pragma unroll
    for (int kb = 0; kb < 4; ++kb) {
      int colg = ks + kb * 16 + ln;
#pragma unroll
      for (int r = 0; r < 4; ++r) {
        float v = sc[kb][r] * SCALE;
        if (diag && colg > rowg + r) v = -1e30f;
        sc[kb][r] = v;
      }
    }
    // online softmax (16-lane groups hold 16 cols for rows g*4+r)
    float corr[4];
#pragma unroll
    for (int r = 0; r < 4; ++r) {
      float m = fmaxf(fmaxf(sc[0][r], sc[1][r]), fmaxf(sc[2][r], sc[3][r]));
#pragma unroll
      for (int off = 8; off >= 1; off >>= 1) m = fmaxf(m, __shfl_xor(m, off));
      float mn = fmaxf(m_run[r], m);
      float c = __expf(m_run[r] - mn);
      m_run[r] = mn;
      float ssum = 0.f;
#pragma unroll
      for (int kb = 0; kb < 4; ++kb) {
        float pv = __expf(sc[kb][r] - mn);
        sc[kb][r] = pv;
        ssum += pv;
      }
#pragma unroll
      for (int off = 8; off >= 1; off >>= 1) ssum += __shfl_xor(ssum, off);
      l_run[r] = l_run[r] * c + ssum;
      corr[r] = c;
    }
#pragma unroll
    for (int cb = 0; cb < 8; ++cb) {
      f32x4 t = acc_o[cb];
      t[0] *= corr[0]; t[1] *= corr[1]; t[2] *= corr[2]; t[3] *= corr[3];
      acc_o[cb] = t;
    }
    // P -> bf16 -> per-wave LDS [16 q][64 k] (stride 72)
#pragma unroll
    for (int kb = 0; kb < 4; ++kb)
#pragma unroll
      for (int r = 0; r < 4; ++r)
        pw[(g * 4 + r) * 72 + kb * 16 + ln] = f2b(sc[kb][r]);
    // PV: O += P * V
#pragma unroll
    for (int st = 0; st < 2; ++st) {
      short8_t pa = *(const short8_t*)(pw + ln * 72 + st * 32 + g * 8);
#pragma unroll
      for (int cb = 0; cb < 8; ++cb) {
        short8_t vf = *(const short8_t*)(VT + (cb * 16 + ln) * 72 + st * 32 + g * 8);
        acc_o[cb] = mfma16(pa, vf, acc_o[cb]);
      }
    }
  }

  float linv[4];
#pragma unroll
  for (int r = 0; r < 4; ++r) linv[r] = 1.0f / l_run[r];
  unsigned short* ob = ao + ((size_t)(b * 2048 + q0 + wave * 16 + g * 4) * 32 + h) * 128;
#pragma unroll
  for (int cb = 0; cb < 8; ++cb)
#pragma unroll
    for (int r = 0; r < 4; ++r)
      ob[(size_t)r * 4096 + cb * 16 + ln] = f2b(acc_o[cb][r] * linv[r]);
}

// ---------------- launch ----------------
extern "C" void kernel_launch(void* const* d_in, const int* in_sizes, int n_in,
                              void* d_out, int out_size, void* d_ws, size_t ws_size,
                              hipStream_t stream) {
  const float* x  = (const float*)d_in[0];
  const float* wq = (const float*)d_in[1];
  const float* wk = (const float*)d_in[2];
  const float* wv = (const float*)d_in[3];
  const float* wo = (const float*)d_in[4];
  const float* fr = (const float*)d_in[7];
  float* out = (float*)d_out;

  char* ws = (char*)d_ws;
  unsigned short* xb  = (unsigned short*)(ws);               // 33.5MB; reused as ao
  unsigned short* wqb = (unsigned short*)(ws + 33554432);    // 33.5MB; reused as wob
  unsigned short* wkb = (unsigned short*)(ws + 67108864);    // 8.4MB
  unsigned short* wvb = (unsigned short*)(ws + 75497472);    // 8.4MB
  unsigned short* xq  = (unsigned short*)(ws + 83886080);    // 33.5MB
  unsigned short* xk  = (unsigned short*)(ws + 117440512);   // 8.4MB
  unsigned short* xvT = (unsigned short*)(ws + 125829120);   // 8.4MB (total 128MiB)
  unsigned short* ao  = xb;
  unsigned short* wob = wqb;

  dim3 blk(256);
  cvt_kernel<<<dim3(1024), blk, 0, stream>>>(x,  xb,  16777216 / 4);
  cvt_kernel<<<dim3(1024), blk, 0, stream>>>(wq, wqb, 16777216 / 4);
  cvt_kernel<<<dim3(512),  blk, 0, stream>>>(wk, wkb, 4194304 / 4);
  cvt_kernel<<<dim3(512),  blk, 0, stream>>>(wv, wvb, 4194304 / 4);

  gemm_qkv_kernel<<<dim3(48, 32), blk, 0, stream>>>(xb, wqb, wkb, wvb, xq, xk, xvT);

  rope_kernel<32><<<dim3(2048), blk, 0, stream>>>(xq, fr, 2097152);
  rope_kernel<8><<<dim3(512),  blk, 0, stream>>>(xk, fr, 524288);

  cvt_kernel<<<dim3(1024), blk, 0, stream>>>(wo, wob, 16777216 / 4);

  attn_kernel<<<dim3(32, 32, 2), blk, 0, stream>>>(xq, xk, xvT, ao);

  gemm_o_kernel<<<dim3(32, 32), blk, 0, stream>>>(ao, wob, out);
}

// Round 6
// 692.341 us; speedup vs baseline: 1.5358x; 1.5358x over previous
//
#include <hip/hip_runtime.h>

typedef __bf16 bf16x8 __attribute__((ext_vector_type(8)));
typedef short short8_t __attribute__((ext_vector_type(8)));
typedef float f32x4 __attribute__((ext_vector_type(4)));
typedef float f32x16 __attribute__((ext_vector_type(16)));
typedef int int2v __attribute__((ext_vector_type(2)));
typedef unsigned short us4_t __attribute__((ext_vector_type(4)));

#define SCALE 0.08838834764831845f  // 1/sqrt(128)
#define CEXP 0.1275179f             // SCALE * log2(e)

__device__ __forceinline__ float b2f(unsigned short u) {
  union { unsigned int i; float f; } v; v.i = ((unsigned int)u) << 16; return v.f;
}
__device__ __forceinline__ unsigned short f2b(float f) {
  union { float f; unsigned int i; } v; v.f = f;
  unsigned int r = v.i + 0x7fffu + ((v.i >> 16) & 1u);
  return (unsigned short)(r >> 16);
}

__device__ __forceinline__ f32x4 mfma16(short8_t a, short8_t b, f32x4 c) {
  return __builtin_amdgcn_mfma_f32_16x16x32_bf16(
      __builtin_bit_cast(bf16x8, a), __builtin_bit_cast(bf16x8, b), c, 0, 0, 0);
}
__device__ __forceinline__ f32x16 mfma32(short8_t a, short8_t b, f32x16 c) {
  return __builtin_amdgcn_mfma_f32_32x32x16_bf16(
      __builtin_bit_cast(bf16x8, a), __builtin_bit_cast(bf16x8, b), c, 0, 0, 0);
}

typedef __attribute__((address_space(1))) const void gas_t;
typedef __attribute__((address_space(3))) void las_t;
__device__ __forceinline__ void gload16(const void* g, void* l) {
  __builtin_amdgcn_global_load_lds((gas_t*)g, (las_t*)l, 16, 0, 0);
}

// ---------------- fp32 -> bf16 convert ----------------
__global__ void cvt_kernel(const float* __restrict__ src, unsigned short* __restrict__ dst, int n4) {
  for (int i = blockIdx.x * blockDim.x + threadIdx.x; i < n4; i += gridDim.x * blockDim.x) {
    f32x4 v = *(const f32x4*)(src + (size_t)i * 4);
    us4_t o;
    o[0] = f2b(v[0]); o[1] = f2b(v[1]); o[2] = f2b(v[2]); o[3] = f2b(v[3]);
    *(us4_t*)(dst + (size_t)i * 4) = o;
  }
}

// ---------------- 128x128 bf16 GEMM core (C = A * Bt^T) ----------------
// MODE: 0 = f32 out, 1 = bf16 out, 2 = bf16 transposed-V out
template <int MODE>
__device__ __forceinline__ void gemm128(const unsigned short* __restrict__ A,
                                        const unsigned short* __restrict__ Bt,
                                        void* __restrict__ Cout,
                                        int m0, int n0, int K, int ldc) {
  __shared__ __align__(16) unsigned short As[128 * 32];
  __shared__ __align__(16) unsigned short Bs[128 * 32];
  const int tid = threadIdx.x;
  const int wave = tid >> 6, lane = tid & 63;
  const int ln = lane & 15, g = lane >> 4;
  const int wm = (wave >> 1) * 64, wn = (wave & 1) * 64;

  const int rA0 = wave * 16 + (lane >> 2);
  const int rA1 = 64 + wave * 16 + (lane >> 2);
  const int colx = (lane & 3) * 8;
  const unsigned short* gA0 = A + (size_t)(m0 + rA0) * K + colx;
  const unsigned short* gA1 = A + (size_t)(m0 + rA1) * K + colx;
  const unsigned short* gB0 = Bt + (size_t)(n0 + rA0) * K + colx;
  const unsigned short* gB1 = Bt + (size_t)(n0 + rA1) * K + colx;
  unsigned short* lA0 = As + wave * 512;
  unsigned short* lA1 = As + 2048 + wave * 512;
  unsigned short* lB0 = Bs + wave * 512;
  unsigned short* lB1 = Bs + 2048 + wave * 512;

  f32x4 acc[4][4] = {};

  for (int k0 = 0; k0 < K; k0 += 32) {
    gload16(gA0 + k0, lA0);
    gload16(gA1 + k0, lA1);
    gload16(gB0 + k0, lB0);
    gload16(gB1 + k0, lB1);
    __syncthreads();
    short8_t a[4], b[4];
#pragma unroll
    for (int i = 0; i < 4; ++i)
      a[i] = *(const short8_t*)(As + (wm + i * 16 + ln) * 32 + g * 8);
#pragma unroll
    for (int j = 0; j < 4; ++j)
      b[j] = *(const short8_t*)(Bs + (wn + j * 16 + ln) * 32 + g * 8);
#pragma unroll
    for (int i = 0; i < 4; ++i)
#pragma unroll
      for (int j = 0; j < 4; ++j)
        acc[i][j] = mfma16(a[i], b[j], acc[i][j]);
    __syncthreads();
  }

#pragma unroll
  for (int i = 0; i < 4; ++i) {
#pragma unroll
    for (int j = 0; j < 4; ++j) {
      if (MODE == 2) {
        int row0 = m0 + wm + i * 16 + g * 4;
        int col = n0 + wn + j * 16 + ln;
        us4_t pk;
#pragma unroll
        for (int r = 0; r < 4; ++r) pk[r] = f2b(acc[i][j][r]);
        *(us4_t*)((unsigned short*)Cout +
                  ((size_t)((row0 >> 11) * 1024 + col)) * 2048 + (row0 & 2047)) = pk;
      } else {
#pragma unroll
        for (int r = 0; r < 4; ++r) {
          int row = m0 + wm + i * 16 + g * 4 + r;
          int col = n0 + wn + j * 16 + ln;
          if (MODE == 1)
            ((unsigned short*)Cout)[(size_t)row * ldc + col] = f2b(acc[i][j][r]);
          else
            ((float*)Cout)[(size_t)row * ldc + col] = acc[i][j][r];
        }
      }
    }
  }
}

__global__ __launch_bounds__(256) void gemm_qkv_kernel(
    const unsigned short* __restrict__ xb, const unsigned short* __restrict__ wqb,
    const unsigned short* __restrict__ wkb, const unsigned short* __restrict__ wvb,
    unsigned short* __restrict__ xq, unsigned short* __restrict__ xk,
    unsigned short* __restrict__ xvT) {
  int bx = blockIdx.x, by = blockIdx.y;
  if (bx < 32)      gemm128<1>(xb, wqb, xq, by * 128, bx * 128, 4096, 4096);
  else if (bx < 40) gemm128<1>(xb, wkb, xk, by * 128, (bx - 32) * 128, 4096, 1024);
  else              gemm128<2>(xb, wvb, xvT, by * 128, (bx - 40) * 128, 4096, 0);
}

__global__ __launch_bounds__(256) void gemm_o_kernel(
    const unsigned short* __restrict__ ao, const unsigned short* __restrict__ wob,
    float* __restrict__ out) {
  gemm128<0>(ao, wob, out, blockIdx.y * 128, blockIdx.x * 128, 4096, 4096);
}

// ---------------- RoPE ----------------
template <int NH>
__global__ void rope_kernel(unsigned short* __restrict__ p, const float* __restrict__ fr,
                            int nchunks) {
  for (int c = blockIdx.x * blockDim.x + threadIdx.x; c < nchunks;
       c += gridDim.x * blockDim.x) {
    size_t e = (size_t)c * 8;
    int f0 = (c & 15) * 4;
    int rest = (int)(e >> 7);
    int s = (rest / NH) & 2047;
    unsigned short* ptr = p + e;
    short8_t v = *(short8_t*)ptr;
    const float* cosp = fr + (size_t)s * 64 + f0;
    const float* sinp = cosp + 131072;
#pragma unroll
    for (int j = 0; j < 4; ++j) {
      float re = b2f((unsigned short)v[2 * j]);
      float im = b2f((unsigned short)v[2 * j + 1]);
      float cc = cosp[j], ss = sinp[j];
      v[2 * j]     = (short)f2b(re * cc - im * ss);
      v[2 * j + 1] = (short)f2b(re * ss + im * cc);
    }
    *(short8_t*)ptr = v;
  }
}

// ---------------- flash attention: 8 waves x 32 q-rows, 32x32 MFMA, swapped QK ----------------
// LDS (bytes): K [0,16384)  [64 k][swizzled 128 d]
//              VT [16384, 34816)  [128 d][72-short stride, 64 k]
//              P  [34816, 55296)  per-wave 2560 B: [32 q][40-short stride, 32 k]
//              cl [55296, 56320)  per-wave 32 floats
__global__ __launch_bounds__(512, 2) void attn_kernel(
    const unsigned short* __restrict__ xq, const unsigned short* __restrict__ xk,
    const unsigned short* __restrict__ xvT, unsigned short* __restrict__ ao) {
  __shared__ __align__(16) unsigned char smem[56320];
  const int tid = threadIdx.x;
  const int wq = tid >> 6, lane = tid & 63;
  const int q31 = lane & 31, hi = lane >> 5;
  const int bx = 7 - (int)blockIdx.x;         // LPT: heaviest first
  const int h = blockIdx.y, b = blockIdx.z;
  const int hkv = h >> 2;
  const int q0 = bx * 256;
  const int a0 = q0 + wq * 32;                // wave's first q row
  const int ktmax_w = a0 >> 6;
  const int NT = bx * 4 + 4;

  const unsigned short* kbase = xk + ((size_t)(b * 2048) * 8 + hkv) * 128;
  const unsigned short* vtg = xvT + (size_t)(b * 1024 + hkv * 128) * 2048;

  // ---- Q fragments (B-operand): col=q31, k-slice d = st*16 + hi*8
  const unsigned short* qrow = xq + ((size_t)(b * 2048 + a0 + q31) * 32 + h) * 128;
  short8_t qf[8];
#pragma unroll
  for (int st = 0; st < 8; ++st) qf[st] = *(const short8_t*)(qrow + st * 16 + hi * 8);

  // ---- K staging geometry (reg-staged, swizzle applied on LDS WRITE address)
  const int c0 = tid, c1 = tid + 512;         // 16B chunks of the 64x128 tile
  const int kg0 = (c0 >> 4) * 1024 + (c0 & 15) * 8;                      // linear src (shorts)
  const int kg1 = (c1 >> 4) * 1024 + (c1 & 15) * 8;
  const int ka0 = (c0 >> 4) * 256 + (((c0 & 15) ^ ((c0 >> 4) & 7)) << 4); // swizzled dst (bytes)
  const int ka1 = (c1 >> 4) * 256 + (((c1 & 15) ^ ((c1 >> 4) & 7)) << 4);
  // ---- VT staging geometry
  const int d0 = tid >> 3, kb0 = tid & 7, d1v = d0 + 64;
  const int vg0 = d0 * 2048 + kb0 * 8, vg1 = d1v * 2048 + kb0 * 8;       // src (shorts)
  const int va0 = d0 * 72 + kb0 * 8, va1 = d1v * 72 + kb0 * 8;           // dst (shorts)

  unsigned short* Kb = (unsigned short*)(smem);
  unsigned short* VT = (unsigned short*)(smem + 16384);
  unsigned short* pp = (unsigned short*)(smem + 34816) + wq * 1280;
  unsigned short* prow = pp + q31 * 40;
  float* cl = (float*)(smem + 55296) + wq * 32;

  f32x16 o[4] = {};
  float m_run = -1e30f, l_run = 0.f;

  // ---- prologue: load tile-0 staging regs
  short8_t kr0 = *(const short8_t*)(kbase + kg0);
  short8_t kr1 = *(const short8_t*)(kbase + kg1);
  short8_t vr0 = *(const short8_t*)(vtg + vg0);
  short8_t vr1 = *(const short8_t*)(vtg + vg1);

  for (int kt = 0; kt < NT; ++kt) {
    // ---- write staged regs to LDS (reads of prev tile finished at last barrier)
    *(short8_t*)((unsigned char*)Kb + ka0) = kr0;
    *(short8_t*)((unsigned char*)Kb + ka1) = kr1;
    *(short8_t*)(VT + va0) = vr0;
    *(short8_t*)(VT + va1) = vr1;
    __syncthreads();
    // ---- prefetch next tile into regs (latency hides under compute)
    if (kt + 1 < NT) {
      const unsigned short* kg = kbase + (size_t)(kt + 1) * 65536;
      kr0 = *(const short8_t*)(kg + kg0);
      kr1 = *(const short8_t*)(kg + kg1);
      vr0 = *(const short8_t*)(vtg + vg0 + (kt + 1) * 64);
      vr1 = *(const short8_t*)(vtg + vg1 + (kt + 1) * 64);
    }

    if (kt <= ktmax_w) {
      // ---- QK^T (A = K rows, B = Q cols) -> P^T fragments
      const int r7 = (q31 & 7) << 4;
      f32x16 p0 = {}, p1 = {};
      __builtin_amdgcn_s_setprio(1);
#pragma unroll
      for (int st = 0; st < 8; ++st) {
        int cb = (((st * 2 + hi) << 4)) ^ r7;
        short8_t k0 = *(const short8_t*)((const unsigned char*)Kb + q31 * 256 + cb);
        short8_t k1 = *(const short8_t*)((const unsigned char*)Kb + (q31 + 32) * 256 + cb);
        p0 = mfma32(k0, qf[st], p0);
        p1 = mfma32(k1, qf[st], p1);
      }
      __builtin_amdgcn_s_setprio(0);

      // ---- causal mask (diag tile only)
      if (kt == ktmax_w) {
        const int q = a0 + q31;
#pragma unroll
        for (int r = 0; r < 16; ++r) {
          int crow = (r & 3) + 8 * (r >> 2) + 4 * hi;
          int kgl = kt * 64 + crow;
          if (kgl > q) p0[r] = -1e30f;
          if (kgl + 32 > q) p1[r] = -1e30f;
        }
      }
      // ---- online softmax (lane owns q-row q31; cross-half via shfl_xor 32)
      float mx = -1e30f;
#pragma unroll
      for (int r = 0; r < 16; ++r) mx = fmaxf(mx, fmaxf(p0[r], p1[r]));
      mx = fmaxf(mx, __shfl_xor(mx, 32));
      float mnew = fmaxf(m_run, mx);
      float corr = exp2f((m_run - mnew) * CEXP);
      m_run = mnew;
      float sum = 0.f;
#pragma unroll
      for (int r = 0; r < 16; ++r) {
        p0[r] = exp2f((p0[r] - mnew) * CEXP);
        p1[r] = exp2f((p1[r] - mnew) * CEXP);
        sum += p0[r] + p1[r];
      }
      sum += __shfl_xor(sum, 32);
      l_run = l_run * corr + sum;

      // ---- broadcast corr across O-fragment rows via per-wave LDS
      cl[q31] = corr;
      f32x4 cv0 = *(const f32x4*)(cl + hi * 4);
      f32x4 cv1 = *(const f32x4*)(cl + 8 + hi * 4);
      f32x4 cv2 = *(const f32x4*)(cl + 16 + hi * 4);
      f32x4 cv3 = *(const f32x4*)(cl + 24 + hi * 4);
#pragma unroll
      for (int db = 0; db < 4; ++db) {
#pragma unroll
        for (int r = 0; r < 4; ++r) {
          o[db][r]      *= cv0[r];
          o[db][4 + r]  *= cv1[r];
          o[db][8 + r]  *= cv2[r];
          o[db][12 + r] *= cv3[r];
        }
      }

      // ---- PV in two k-halves: P bounce through per-wave LDS, then mfma
      // half A: k 0..31 (p0)
#pragma unroll
      for (int u = 0; u < 4; ++u) {
        int2v w;
        w[0] = (int)((unsigned)f2b(p0[4 * u]) | ((unsigned)f2b(p0[4 * u + 1]) << 16));
        w[1] = (int)((unsigned)f2b(p0[4 * u + 2]) | ((unsigned)f2b(p0[4 * u + 3]) << 16));
        *(int2v*)(prow + u * 8 + hi * 4) = w;
      }
      {
        short8_t pa0 = *(const short8_t*)(prow + hi * 8);
        short8_t pa1 = *(const short8_t*)(prow + 16 + hi * 8);
        __builtin_amdgcn_s_setprio(1);
#pragma unroll
        for (int db = 0; db < 4; ++db) {
          const unsigned short* vtd = VT + (db * 32 + q31) * 72;
          short8_t vf0 = *(const short8_t*)(vtd + hi * 8);
          short8_t vf1 = *(const short8_t*)(vtd + 16 + hi * 8);
          o[db] = mfma32(pa0, vf0, o[db]);
          o[db] = mfma32(pa1, vf1, o[db]);
        }
        __builtin_amdgcn_s_setprio(0);
      }
      // half B: k 32..63 (p1), reuses the same P region
#pragma unroll
      for (int u = 0; u < 4; ++u) {
        int2v w;
        w[0] = (int)((unsigned)f2b(p1[4 * u]) | ((unsigned)f2b(p1[4 * u + 1]) << 16));
        w[1] = (int)((unsigned)f2b(p1[4 * u + 2]) | ((unsigned)f2b(p1[4 * u + 3]) << 16));
        *(int2v*)(prow + u * 8 + hi * 4) = w;
      }
      {
        short8_t pa2 = *(const short8_t*)(prow + hi * 8);
        short8_t pa3 = *(const short8_t*)(prow + 16 + hi * 8);
        __builtin_amdgcn_s_setprio(1);
#pragma unroll
        for (int db = 0; db < 4; ++db) {
          const unsigned short* vtd = VT + (db * 32 + q31) * 72;
          short8_t vf2 = *(const short8_t*)(vtd + 32 + hi * 8);
          short8_t vf3 = *(const short8_t*)(vtd + 48 + hi * 8);
          o[db] = mfma32(pa2, vf2, o[db]);
          o[db] = mfma32(pa3, vf3, o[db]);
        }
        __builtin_amdgcn_s_setprio(0);
      }
    }
    __syncthreads();
  }

  // ---- epilogue: divide by l, store bf16
  cl[q31] = l_run;
  f32x4 lv0 = *(const f32x4*)(cl + hi * 4);
  f32x4 lv1 = *(const f32x4*)(cl + 8 + hi * 4);
  f32x4 lv2 = *(const f32x4*)(cl + 16 + hi * 4);
  f32x4 lv3 = *(const f32x4*)(cl + 24 + hi * 4);
  f32x4 iv0, iv1, iv2, iv3;
#pragma unroll
  for (int r = 0; r < 4; ++r) {
    iv0[r] = 1.0f / lv0[r]; iv1[r] = 1.0f / lv1[r];
    iv2[r] = 1.0f / lv2[r]; iv3[r] = 1.0f / lv3[r];
  }
  unsigned short* ob = ao + ((size_t)(b * 2048 + a0) * 32 + h) * 128;
#pragma unroll
  for (int db = 0; db < 4; ++db) {
#pragma unroll
    for (int r = 0; r < 16; ++r) {
      int crow = (r & 3) + 8 * (r >> 2) + 4 * hi;
      float iv = (r < 4) ? iv0[r & 3] : (r < 8) ? iv1[r & 3] : (r < 12) ? iv2[r & 3] : iv3[r & 3];
      ob[(size_t)crow * 4096 + db * 32 + q31] = f2b(o[db][r] * iv);
    }
  }
}

// ---------------- launch ----------------
extern "C" void kernel_launch(void* const* d_in, const int* in_sizes, int n_in,
                              void* d_out, int out_size, void* d_ws, size_t ws_size,
                              hipStream_t stream) {
  const float* x  = (const float*)d_in[0];
  const float* wq = (const float*)d_in[1];
  const float* wk = (const float*)d_in[2];
  const float* wv = (const float*)d_in[3];
  const float* wo = (const float*)d_in[4];
  const float* fr = (const float*)d_in[7];
  float* out = (float*)d_out;

  char* ws = (char*)d_ws;
  unsigned short* xb  = (unsigned short*)(ws);               // 33.5MB; reused as ao
  unsigned short* wqb = (unsigned short*)(ws + 33554432);    // 33.5MB; reused as wob
  unsigned short* wkb = (unsigned short*)(ws + 67108864);    // 8.4MB
  unsigned short* wvb = (unsigned short*)(ws + 75497472);    // 8.4MB
  unsigned short* xq  = (unsigned short*)(ws + 83886080);    // 33.5MB
  unsigned short* xk  = (unsigned short*)(ws + 117440512);   // 8.4MB
  unsigned short* xvT = (unsigned short*)(ws + 125829120);   // 8.4MB (total 128MiB)
  unsigned short* ao  = xb;
  unsigned short* wob = wqb;

  dim3 blk(256);
  cvt_kernel<<<dim3(1024), blk, 0, stream>>>(x,  xb,  16777216 / 4);
  cvt_kernel<<<dim3(1024), blk, 0, stream>>>(wq, wqb, 16777216 / 4);
  cvt_kernel<<<dim3(512),  blk, 0, stream>>>(wk, wkb, 4194304 / 4);
  cvt_kernel<<<dim3(512),  blk, 0, stream>>>(wv, wvb, 4194304 / 4);

  gemm_qkv_kernel<<<dim3(48, 32), blk, 0, stream>>>(xb, wqb, wkb, wvb, xq, xk, xvT);

  rope_kernel<32><<<dim3(2048), blk, 0, stream>>>(xq, fr, 2097152);
  rope_kernel<8><<<dim3(512),  blk, 0, stream>>>(xk, fr, 524288);

  cvt_kernel<<<dim3(1024), blk, 0, stream>>>(wo, wob, 16777216 / 4);

  attn_kernel<<<dim3(8, 32, 2), dim3(512), 0, stream>>>(xq, xk, xvT, ao);

  gemm_o_kernel<<<dim3(32, 32), blk, 0, stream>>>(ao, wob, out);
}

// Round 11
// 644.525 us; speedup vs baseline: 1.6497x; 1.0742x over previous
//
#include <hip/hip_runtime.h>

typedef __bf16 bf16x8 __attribute__((ext_vector_type(8)));
typedef short short8_t __attribute__((ext_vector_type(8)));
typedef float f32x4 __attribute__((ext_vector_type(4)));
typedef float f32x16 __attribute__((ext_vector_type(16)));
typedef int int2v __attribute__((ext_vector_type(2)));
typedef unsigned short us4_t __attribute__((ext_vector_type(4)));

#define SCALE 0.08838834764831845f  // 1/sqrt(128)
#define CEXP 0.1275179f             // SCALE * log2(e)

#define VMCNT(n) asm volatile("s_waitcnt vmcnt(" #n ")" ::: "memory")

__device__ __forceinline__ float b2f(unsigned short u) {
  union { unsigned int i; float f; } v; v.i = ((unsigned int)u) << 16; return v.f;
}
__device__ __forceinline__ unsigned short f2b(float f) {
  union { float f; unsigned int i; } v; v.f = f;
  unsigned int r = v.i + 0x7fffu + ((v.i >> 16) & 1u);
  return (unsigned short)(r >> 16);
}

__device__ __forceinline__ f32x4 mfma16(short8_t a, short8_t b, f32x4 c) {
  return __builtin_amdgcn_mfma_f32_16x16x32_bf16(
      __builtin_bit_cast(bf16x8, a), __builtin_bit_cast(bf16x8, b), c, 0, 0, 0);
}
__device__ __forceinline__ f32x16 mfma32(short8_t a, short8_t b, f32x16 c) {
  return __builtin_amdgcn_mfma_f32_32x32x16_bf16(
      __builtin_bit_cast(bf16x8, a), __builtin_bit_cast(bf16x8, b), c, 0, 0, 0);
}

typedef __attribute__((address_space(1))) const void gas_t;
typedef __attribute__((address_space(3))) void las_t;
__device__ __forceinline__ void gload16(const void* g, void* l) {
  __builtin_amdgcn_global_load_lds((gas_t*)g, (las_t*)l, 16, 0, 0);
}

// ---------------- fp32 -> bf16 convert ----------------
__global__ void cvt_kernel(const float* __restrict__ src, unsigned short* __restrict__ dst, int n4) {
  for (int i = blockIdx.x * blockDim.x + threadIdx.x; i < n4; i += gridDim.x * blockDim.x) {
    f32x4 v = *(const f32x4*)(src + (size_t)i * 4);
    us4_t o;
    o[0] = f2b(v[0]); o[1] = f2b(v[1]); o[2] = f2b(v[2]); o[3] = f2b(v[3]);
    *(us4_t*)(dst + (size_t)i * 4) = o;
  }
}

// ============ 256x256 counted-vmcnt pipelined GEMM core (C = A * Bt^T) ============
// BK=32, 4 LDS slots (stage lead 3), 8 waves (2M x 4N), 2 phases/K-tile.
// LDS layout (shorts): A-slots [0,32768): slot s at s*8192; B-slots [32768,65536).
// Within a tile: element (r, k-block j in 16B units) stored at byte
//   r*64 + (j ^ ((r>>1)&3))*16  — both staging source and ds_read use this XOR.
// MODE: 0 = f32 out, 1 = bf16 out, 2 = bf16 transposed-V out
// NOTE: the 128 KiB LDS block is DECLARED IN THE KERNEL and passed in, so
// multiple template instantiations in one kernel share one allocation.
template <int MODE>
__device__ __forceinline__ void gemm256_core(
    unsigned short* __restrict__ lds,
    const unsigned short* __restrict__ A, const unsigned short* __restrict__ Bt,
    void* __restrict__ Cout, int m0, int n0, int K, int ldc) {
  const int tid = threadIdx.x;
  const int wid = tid >> 6, lane = tid & 63;
  const int ln = lane & 15, lg = lane >> 4;
  const int wm = wid >> 2, wn = wid & 3;
  const int NT = K >> 5;

  // ---- staging geometry: per gload round, wave covers 16 rows (of 256)
  const int sr0 = wid * 16 + (lane >> 2);
  const int sr1 = 128 + sr0;
  const int sj0 = ((lane & 3) ^ ((sr0 >> 1) & 3)) * 8;   // inverse-swizzled source block
  const int sj1 = ((lane & 3) ^ ((sr1 >> 1) & 3)) * 8;
  const unsigned short* gA0 = A + (size_t)(m0 + sr0) * K + sj0;
  const unsigned short* gA1 = A + (size_t)(m0 + sr1) * K + sj1;
  const unsigned short* gB0 = Bt + (size_t)(n0 + sr0) * K + sj0;
  const unsigned short* gB1 = Bt + (size_t)(n0 + sr1) * K + sj1;
  unsigned short* dA = lds + wid * 512;            // + s*8192 (+4096 for g=1), shorts
  unsigned short* dB = lds + 32768 + wid * 512;

  // ---- ds_read fragment addressing (bytes)
  const int swz = (ln >> 1) & 3;
  const int jA = (lg ^ swz) << 4;
  const unsigned char* ldsb = (const unsigned char*)lds;
  const int aoff = (wm * 128 + ln) * 64 + jA;            // + mi*1024 + slot*16384
  const int boff = 65536 + (wn * 64 + ln) * 64 + jA;     // + nj*1024 + slot*16384

  f32x4 acc[8][4] = {};

#define STAGE_A(t_) { int s_ = (t_) & 3; int k0_ = (t_) << 5; \
    gload16(gA0 + k0_, dA + s_ * 8192); \
    gload16(gA1 + k0_, dA + s_ * 8192 + 4096); }
#define STAGE_B(t_) { int s_ = (t_) & 3; int k0_ = (t_) << 5; \
    gload16(gB0 + k0_, dB + s_ * 8192); \
    gload16(gB1 + k0_, dB + s_ * 8192 + 4096); }

  // prologue: stage tiles 0,1,2; confirm tile 0 (8 newer loads stay in flight)
  STAGE_A(0); STAGE_B(0);
  STAGE_A(1); STAGE_B(1);
  STAGE_A(2); STAGE_B(2);
  VMCNT(8);
  __builtin_amdgcn_s_barrier();

  for (int t = 0; t < NT; ++t) {
    const int sb = (t & 3) * 16384;
    // ---------- phase A: stage A(t+3) | read A-frags + B01 | barrier | 16 MFMA ----------
    if (t + 3 < NT) STAGE_A(t + 3);
    short8_t af[8], bf0, bf1;
#pragma unroll
    for (int mi = 0; mi < 8; ++mi)
      af[mi] = *(const short8_t*)(ldsb + sb + aoff + mi * 1024);
    bf0 = *(const short8_t*)(ldsb + sb + boff);
    bf1 = *(const short8_t*)(ldsb + sb + boff + 1024);
    __builtin_amdgcn_s_barrier();
    asm volatile("s_waitcnt lgkmcnt(0)" ::: "memory");
    __builtin_amdgcn_sched_barrier(0);
    __builtin_amdgcn_s_setprio(1);
#pragma unroll
    for (int mi = 0; mi < 8; ++mi) {
      acc[mi][0] = mfma16(af[mi], bf0, acc[mi][0]);
      acc[mi][1] = mfma16(af[mi], bf1, acc[mi][1]);
    }
    __builtin_amdgcn_s_setprio(0);
    __builtin_amdgcn_s_barrier();
    // ---------- phase B: stage B(t+3) | read B23 | vmcnt(N) | barrier | 16 MFMA ----------
    if (t + 3 < NT) STAGE_B(t + 3);
    short8_t bf2 = *(const short8_t*)(ldsb + sb + boff + 2048);
    short8_t bf3 = *(const short8_t*)(ldsb + sb + boff + 3072);
    if (t < NT - 3) { VMCNT(8); }        // confirm stage(t+1); keep 8 in flight
    else if (t == NT - 3) { VMCNT(4); }  // tail drain 8 -> 4 -> 0
    else if (t == NT - 2) { VMCNT(0); }
    __builtin_amdgcn_s_barrier();
    asm volatile("s_waitcnt lgkmcnt(0)" ::: "memory");
    __builtin_amdgcn_sched_barrier(0);
    __builtin_amdgcn_s_setprio(1);
#pragma unroll
    for (int mi = 0; mi < 8; ++mi) {
      acc[mi][2] = mfma16(af[mi], bf2, acc[mi][2]);
      acc[mi][3] = mfma16(af[mi], bf3, acc[mi][3]);
    }
    __builtin_amdgcn_s_setprio(0);
    __builtin_amdgcn_s_barrier();
  }
#undef STAGE_A
#undef STAGE_B

  // ---------- epilogue ----------
#pragma unroll
  for (int mi = 0; mi < 8; ++mi) {
#pragma unroll
    for (int nj = 0; nj < 4; ++nj) {
      if (MODE == 2) {
        int row0 = m0 + wm * 128 + mi * 16 + lg * 4;
        int col = n0 + wn * 64 + nj * 16 + ln;
        us4_t pk;
#pragma unroll
        for (int r = 0; r < 4; ++r) pk[r] = f2b(acc[mi][nj][r]);
        *(us4_t*)((unsigned short*)Cout +
                  ((size_t)((row0 >> 11) * 1024 + col)) * 2048 + (row0 & 2047)) = pk;
      } else {
#pragma unroll
        for (int r = 0; r < 4; ++r) {
          int row = m0 + wm * 128 + mi * 16 + lg * 4 + r;
          int col = n0 + wn * 64 + nj * 16 + ln;
          if (MODE == 1)
            ((unsigned short*)Cout)[(size_t)row * ldc + col] = f2b(acc[mi][nj][r]);
          else
            ((float*)Cout)[(size_t)row * ldc + col] = acc[mi][nj][r];
        }
      }
    }
  }
}

// QKV: grid (24, 16). ct<16 -> Q, 16..19 -> K, 20..23 -> V(transposed store).
__global__ __launch_bounds__(512, 1) void gemm_qkv_kernel(
    const unsigned short* __restrict__ xb, const unsigned short* __restrict__ wqb,
    const unsigned short* __restrict__ wkb, const unsigned short* __restrict__ wvb,
    unsigned short* __restrict__ xq, unsigned short* __restrict__ xk,
    unsigned short* __restrict__ xvT) {
  __shared__ __align__(16) unsigned short lds[65536];  // 128 KiB, shared by all modes
  int ct = blockIdx.x, mt = blockIdx.y;
  if (ct < 16)      gemm256_core<1>(lds, xb, wqb, xq, mt * 256, ct * 256, 4096, 4096);
  else if (ct < 20) gemm256_core<1>(lds, xb, wkb, xk, mt * 256, (ct - 16) * 256, 4096, 1024);
  else              gemm256_core<2>(lds, xb, wvb, xvT, mt * 256, (ct - 20) * 256, 4096, 0);
}

__global__ __launch_bounds__(512, 1) void gemm_o_kernel(
    const unsigned short* __restrict__ ao, const unsigned short* __restrict__ wob,
    float* __restrict__ out) {
  __shared__ __align__(16) unsigned short lds[65536];
  gemm256_core<0>(lds, ao, wob, out, blockIdx.y * 256, blockIdx.x * 256, 4096, 4096);
}

// ---------------- RoPE ----------------
template <int NH>
__global__ void rope_kernel(unsigned short* __restrict__ p, const float* __restrict__ fr,
                            int nchunks) {
  for (int c = blockIdx.x * blockDim.x + threadIdx.x; c < nchunks;
       c += gridDim.x * blockDim.x) {
    size_t e = (size_t)c * 8;
    int f0 = (c & 15) * 4;
    int rest = (int)(e >> 7);
    int s = (rest / NH) & 2047;
    unsigned short* ptr = p + e;
    short8_t v = *(short8_t*)ptr;
    const float* cosp = fr + (size_t)s * 64 + f0;
    const float* sinp = cosp + 131072;
#pragma unroll
    for (int j = 0; j < 4; ++j) {
      float re = b2f((unsigned short)v[2 * j]);
      float im = b2f((unsigned short)v[2 * j + 1]);
      float cc = cosp[j], ss = sinp[j];
      v[2 * j]     = (short)f2b(re * cc - im * ss);
      v[2 * j + 1] = (short)f2b(re * ss + im * cc);
    }
    *(short8_t*)ptr = v;
  }
}

// ---------------- flash attention (Round-6 verified): 8 waves x 32 q-rows, 32x32 MFMA ----------------
__global__ __launch_bounds__(512, 2) void attn_kernel(
    const unsigned short* __restrict__ xq, const unsigned short* __restrict__ xk,
    const unsigned short* __restrict__ xvT, unsigned short* __restrict__ ao) {
  __shared__ __align__(16) unsigned char smem[56320];
  const int tid = threadIdx.x;
  const int wq = tid >> 6, lane = tid & 63;
  const int q31 = lane & 31, hi = lane >> 5;
  const int bx = 7 - (int)blockIdx.x;         // LPT: heaviest first
  const int h = blockIdx.y, b = blockIdx.z;
  const int hkv = h >> 2;
  const int q0 = bx * 256;
  const int a0 = q0 + wq * 32;
  const int ktmax_w = a0 >> 6;
  const int NT = bx * 4 + 4;

  const unsigned short* kbase = xk + ((size_t)(b * 2048) * 8 + hkv) * 128;
  const unsigned short* vtg = xvT + (size_t)(b * 1024 + hkv * 128) * 2048;

  const unsigned short* qrow = xq + ((size_t)(b * 2048 + a0 + q31) * 32 + h) * 128;
  short8_t qf[8];
#pragma unroll
  for (int st = 0; st < 8; ++st) qf[st] = *(const short8_t*)(qrow + st * 16 + hi * 8);

  const int c0 = tid, c1 = tid + 512;
  const int kg0 = (c0 >> 4) * 1024 + (c0 & 15) * 8;
  const int kg1 = (c1 >> 4) * 1024 + (c1 & 15) * 8;
  const int ka0 = (c0 >> 4) * 256 + (((c0 & 15) ^ ((c0 >> 4) & 7)) << 4);
  const int ka1 = (c1 >> 4) * 256 + (((c1 & 15) ^ ((c1 >> 4) & 7)) << 4);
  const int d0 = tid >> 3, kb0 = tid & 7, d1v = d0 + 64;
  const int vg0 = d0 * 2048 + kb0 * 8, vg1 = d1v * 2048 + kb0 * 8;
  const int va0 = d0 * 72 + kb0 * 8, va1 = d1v * 72 + kb0 * 8;

  unsigned short* Kb = (unsigned short*)(smem);
  unsigned short* VT = (unsigned short*)(smem + 16384);
  unsigned short* pp = (unsigned short*)(smem + 34816) + wq * 1280;
  unsigned short* prow = pp + q31 * 40;
  float* cl = (float*)(smem + 55296) + wq * 32;

  f32x16 o[4] = {};
  float m_run = -1e30f, l_run = 0.f;

  short8_t kr0 = *(const short8_t*)(kbase + kg0);
  short8_t kr1 = *(const short8_t*)(kbase + kg1);
  short8_t vr0 = *(const short8_t*)(vtg + vg0);
  short8_t vr1 = *(const short8_t*)(vtg + vg1);

  for (int kt = 0; kt < NT; ++kt) {
    *(short8_t*)((unsigned char*)Kb + ka0) = kr0;
    *(short8_t*)((unsigned char*)Kb + ka1) = kr1;
    *(short8_t*)(VT + va0) = vr0;
    *(short8_t*)(VT + va1) = vr1;
    __syncthreads();
    if (kt + 1 < NT) {
      const unsigned short* kg = kbase + (size_t)(kt + 1) * 65536;
      kr0 = *(const short8_t*)(kg + kg0);
      kr1 = *(const short8_t*)(kg + kg1);
      vr0 = *(const short8_t*)(vtg + vg0 + (kt + 1) * 64);
      vr1 = *(const short8_t*)(vtg + vg1 + (kt + 1) * 64);
    }

    if (kt <= ktmax_w) {
      const int r7 = (q31 & 7) << 4;
      f32x16 p0 = {}, p1 = {};
      __builtin_amdgcn_s_setprio(1);
#pragma unroll
      for (int st = 0; st < 8; ++st) {
        int cb = (((st * 2 + hi) << 4)) ^ r7;
        short8_t k0 = *(const short8_t*)((const unsigned char*)Kb + q31 * 256 + cb);
        short8_t k1 = *(const short8_t*)((const unsigned char*)Kb + (q31 + 32) * 256 + cb);
        p0 = mfma32(k0, qf[st], p0);
        p1 = mfma32(k1, qf[st], p1);
      }
      __builtin_amdgcn_s_setprio(0);

      if (kt == ktmax_w) {
        const int q = a0 + q31;
#pragma unroll
        for (int r = 0; r < 16; ++r) {
          int crow = (r & 3) + 8 * (r >> 2) + 4 * hi;
          int kgl = kt * 64 + crow;
          if (kgl > q) p0[r] = -1e30f;
          if (kgl + 32 > q) p1[r] = -1e30f;
        }
      }
      float mx = -1e30f;
#pragma unroll
      for (int r = 0; r < 16; ++r) mx = fmaxf(mx, fmaxf(p0[r], p1[r]));
      mx = fmaxf(mx, __shfl_xor(mx, 32));
      float mnew = fmaxf(m_run, mx);
      float corr = exp2f((m_run - mnew) * CEXP);
      m_run = mnew;
      float sum = 0.f;
#pragma unroll
      for (int r = 0; r < 16; ++r) {
        p0[r] = exp2f((p0[r] - mnew) * CEXP);
        p1[r] = exp2f((p1[r] - mnew) * CEXP);
        sum += p0[r] + p1[r];
      }
      sum += __shfl_xor(sum, 32);
      l_run = l_run * corr + sum;

      cl[q31] = corr;
      f32x4 cv0 = *(const f32x4*)(cl + hi * 4);
      f32x4 cv1 = *(const f32x4*)(cl + 8 + hi * 4);
      f32x4 cv2 = *(const f32x4*)(cl + 16 + hi * 4);
      f32x4 cv3 = *(const f32x4*)(cl + 24 + hi * 4);
#pragma unroll
      for (int db = 0; db < 4; ++db) {
#pragma unroll
        for (int r = 0; r < 4; ++r) {
          o[db][r]      *= cv0[r];
          o[db][4 + r]  *= cv1[r];
          o[db][8 + r]  *= cv2[r];
          o[db][12 + r] *= cv3[r];
        }
      }

#pragma unroll
      for (int u = 0; u < 4; ++u) {
        int2v w;
        w[0] = (int)((unsigned)f2b(p0[4 * u]) | ((unsigned)f2b(p0[4 * u + 1]) << 16));
        w[1] = (int)((unsigned)f2b(p0[4 * u + 2]) | ((unsigned)f2b(p0[4 * u + 3]) << 16));
        *(int2v*)(prow + u * 8 + hi * 4) = w;
      }
      {
        short8_t pa0 = *(const short8_t*)(prow + hi * 8);
        short8_t pa1 = *(const short8_t*)(prow + 16 + hi * 8);
        __builtin_amdgcn_s_setprio(1);
#pragma unroll
        for (int db = 0; db < 4; ++db) {
          const unsigned short* vtd = VT + (db * 32 + q31) * 72;
          short8_t vf0 = *(const short8_t*)(vtd + hi * 8);
          short8_t vf1 = *(const short8_t*)(vtd + 16 + hi * 8);
          o[db] = mfma32(pa0, vf0, o[db]);
          o[db] = mfma32(pa1, vf1, o[db]);
        }
        __builtin_amdgcn_s_setprio(0);
      }
#pragma unroll
      for (int u = 0; u < 4; ++u) {
        int2v w;
        w[0] = (int)((unsigned)f2b(p1[4 * u]) | ((unsigned)f2b(p1[4 * u + 1]) << 16));
        w[1] = (int)((unsigned)f2b(p1[4 * u + 2]) | ((unsigned)f2b(p1[4 * u + 3]) << 16));
        *(int2v*)(prow + u * 8 + hi * 4) = w;
      }
      {
        short8_t pa2 = *(const short8_t*)(prow + hi * 8);
        short8_t pa3 = *(const short8_t*)(prow + 16 + hi * 8);
        __builtin_amdgcn_s_setprio(1);
#pragma unroll
        for (int db = 0; db < 4; ++db) {
          const unsigned short* vtd = VT + (db * 32 + q31) * 72;
          short8_t vf2 = *(const short8_t*)(vtd + 32 + hi * 8);
          short8_t vf3 = *(const short8_t*)(vtd + 48 + hi * 8);
          o[db] = mfma32(pa2, vf2, o[db]);
          o[db] = mfma32(pa3, vf3, o[db]);
        }
        __builtin_amdgcn_s_setprio(0);
      }
    }
    __syncthreads();
  }

  cl[q31] = l_run;
  f32x4 lv0 = *(const f32x4*)(cl + hi * 4);
  f32x4 lv1 = *(const f32x4*)(cl + 8 + hi * 4);
  f32x4 lv2 = *(const f32x4*)(cl + 16 + hi * 4);
  f32x4 lv3 = *(const f32x4*)(cl + 24 + hi * 4);
  f32x4 iv0, iv1, iv2, iv3;
#pragma unroll
  for (int r = 0; r < 4; ++r) {
    iv0[r] = 1.0f / lv0[r]; iv1[r] = 1.0f / lv1[r];
    iv2[r] = 1.0f / lv2[r]; iv3[r] = 1.0f / lv3[r];
  }
  unsigned short* ob = ao + ((size_t)(b * 2048 + a0) * 32 + h) * 128;
#pragma unroll
  for (int db = 0; db < 4; ++db) {
#pragma unroll
    for (int r = 0; r < 16; ++r) {
      int crow = (r & 3) + 8 * (r >> 2) + 4 * hi;
      float iv = (r < 4) ? iv0[r & 3] : (r < 8) ? iv1[r & 3] : (r < 12) ? iv2[r & 3] : iv3[r & 3];
      ob[(size_t)crow * 4096 + db * 32 + q31] = f2b(o[db][r] * iv);
    }
  }
}

// ---------------- launch ----------------
extern "C" void kernel_launch(void* const* d_in, const int* in_sizes, int n_in,
                              void* d_out, int out_size, void* d_ws, size_t ws_size,
                              hipStream_t stream) {
  const float* x  = (const float*)d_in[0];
  const float* wq = (const float*)d_in[1];
  const float* wk = (const float*)d_in[2];
  const float* wv = (const float*)d_in[3];
  const float* wo = (const float*)d_in[4];
  const float* fr = (const float*)d_in[7];
  float* out = (float*)d_out;

  char* ws = (char*)d_ws;
  unsigned short* xb  = (unsigned short*)(ws);               // 33.5MB; reused as ao
  unsigned short* wqb = (unsigned short*)(ws + 33554432);    // 33.5MB; reused as wob
  unsigned short* wkb = (unsigned short*)(ws + 67108864);    // 8.4MB
  unsigned short* wvb = (unsigned short*)(ws + 75497472);    // 8.4MB
  unsigned short* xq  = (unsigned short*)(ws + 83886080);    // 33.5MB
  unsigned short* xk  = (unsigned short*)(ws + 117440512);   // 8.4MB
  unsigned short* xvT = (unsigned short*)(ws + 125829120);   // 8.4MB (total 128MiB)
  unsigned short* ao  = xb;
  unsigned short* wob = wqb;

  dim3 blk(256);
  cvt_kernel<<<dim3(1024), blk, 0, stream>>>(x,  xb,  16777216 / 4);
  cvt_kernel<<<dim3(1024), blk, 0, stream>>>(wq, wqb, 16777216 / 4);
  cvt_kernel<<<dim3(512),  blk, 0, stream>>>(wk, wkb, 4194304 / 4);
  cvt_kernel<<<dim3(512),  blk, 0, stream>>>(wv, wvb, 4194304 / 4);

  gemm_qkv_kernel<<<dim3(24, 16), dim3(512), 0, stream>>>(xb, wqb, wkb, wvb, xq, xk, xvT);

  rope_kernel<32><<<dim3(2048), blk, 0, stream>>>(xq, fr, 2097152);
  rope_kernel<8><<<dim3(512),  blk, 0, stream>>>(xk, fr, 524288);

  cvt_kernel<<<dim3(1024), blk, 0, stream>>>(wo, wob, 16777216 / 4);

  attn_kernel<<<dim3(8, 32, 2), dim3(512), 0, stream>>>(xq, xk, xvT, ao);

  gemm_o_kernel<<<dim3(16, 16), dim3(512), 0, stream>>>(ao, wob, out);
}

// Round 12
// 638.481 us; speedup vs baseline: 1.6653x; 1.0095x over previous
//
#include <hip/hip_runtime.h>

typedef __bf16 bf16x8 __attribute__((ext_vector_type(8)));
typedef short short8_t __attribute__((ext_vector_type(8)));
typedef float f32x4 __attribute__((ext_vector_type(4)));
typedef float f32x16 __attribute__((ext_vector_type(16)));
typedef int int2v __attribute__((ext_vector_type(2)));
typedef unsigned short us4_t __attribute__((ext_vector_type(4)));

#define SCALE 0.08838834764831845f  // 1/sqrt(128)
#define CEXP 0.1275179f             // SCALE * log2(e)

#define VMCNT(n) asm volatile("s_waitcnt vmcnt(" #n ")" ::: "memory")

__device__ __forceinline__ float b2f(unsigned short u) {
  union { unsigned int i; float f; } v; v.i = ((unsigned int)u) << 16; return v.f;
}
__device__ __forceinline__ unsigned short f2b(float f) {
  union { float f; unsigned int i; } v; v.f = f;
  unsigned int r = v.i + 0x7fffu + ((v.i >> 16) & 1u);
  return (unsigned short)(r >> 16);
}

__device__ __forceinline__ f32x4 mfma16(short8_t a, short8_t b, f32x4 c) {
  return __builtin_amdgcn_mfma_f32_16x16x32_bf16(
      __builtin_bit_cast(bf16x8, a), __builtin_bit_cast(bf16x8, b), c, 0, 0, 0);
}
__device__ __forceinline__ f32x16 mfma32(short8_t a, short8_t b, f32x16 c) {
  return __builtin_amdgcn_mfma_f32_32x32x16_bf16(
      __builtin_bit_cast(bf16x8, a), __builtin_bit_cast(bf16x8, b), c, 0, 0, 0);
}

typedef __attribute__((address_space(1))) const void gas_t;
typedef __attribute__((address_space(3))) void las_t;
__device__ __forceinline__ void gload16(const void* g, void* l) {
  __builtin_amdgcn_global_load_lds((gas_t*)g, (las_t*)l, 16, 0, 0);
}

// ---------------- fp32 -> bf16 convert ----------------
__global__ void cvt_kernel(const float* __restrict__ src, unsigned short* __restrict__ dst, int n4) {
  for (int i = blockIdx.x * blockDim.x + threadIdx.x; i < n4; i += gridDim.x * blockDim.x) {
    f32x4 v = *(const f32x4*)(src + (size_t)i * 4);
    us4_t o;
    o[0] = f2b(v[0]); o[1] = f2b(v[1]); o[2] = f2b(v[2]); o[3] = f2b(v[3]);
    *(us4_t*)(dst + (size_t)i * 4) = o;
  }
}

// ============ 256x256 counted-vmcnt pipelined GEMM core (C = A * Bt^T) ============
// BK=32, 4 LDS slots (stage lead 3), 8 waves (2M x 4N), ONE phase per K-tile:
//   stage(t+3) | read all 12 frags | vmcnt(8) | barrier | lgkm(0) | 32 MFMA | barrier
// Slot t&3 is fully landed (confirmed by tile t-1's vmcnt) before any read.
// LDS layout (shorts): A-slots [0,32768): slot s at s*8192; B-slots [32768,65536).
// Within a tile: element (r, k-block j in 16B units) stored at byte
//   r*64 + (j ^ ((r>>1)&3))*16  — both staging source and ds_read use this XOR.
// MODE: 0 = f32 out, 1 = bf16 out, 2 = bf16 transposed-V out
template <int MODE>
__device__ __forceinline__ void gemm256_core(
    unsigned short* __restrict__ lds,
    const unsigned short* __restrict__ A, const unsigned short* __restrict__ Bt,
    void* __restrict__ Cout, int m0, int n0, int K, int ldc) {
  const int tid = threadIdx.x;
  const int wid = tid >> 6, lane = tid & 63;
  const int ln = lane & 15, lg = lane >> 4;
  const int wm = wid >> 2, wn = wid & 3;
  const int NT = K >> 5;

  // ---- staging geometry: per gload round, wave covers 16 rows (of 256)
  const int sr0 = wid * 16 + (lane >> 2);
  const int sr1 = 128 + sr0;
  const int sj0 = ((lane & 3) ^ ((sr0 >> 1) & 3)) * 8;   // inverse-swizzled source block
  const int sj1 = ((lane & 3) ^ ((sr1 >> 1) & 3)) * 8;
  const unsigned short* gA0 = A + (size_t)(m0 + sr0) * K + sj0;
  const unsigned short* gA1 = A + (size_t)(m0 + sr1) * K + sj1;
  const unsigned short* gB0 = Bt + (size_t)(n0 + sr0) * K + sj0;
  const unsigned short* gB1 = Bt + (size_t)(n0 + sr1) * K + sj1;
  unsigned short* dA = lds + wid * 512;            // + s*8192 (+4096 for g=1), shorts
  unsigned short* dB = lds + 32768 + wid * 512;

  // ---- ds_read fragment addressing (bytes)
  const int swz = (ln >> 1) & 3;
  const int jA = (lg ^ swz) << 4;
  const unsigned char* ldsb = (const unsigned char*)lds;
  const int aoff = (wm * 128 + ln) * 64 + jA;            // + mi*1024 + slot*16384
  const int boff = 65536 + (wn * 64 + ln) * 64 + jA;     // + nj*1024 + slot*16384

  f32x4 acc[8][4] = {};

#define STAGE_A(t_) { int s_ = (t_) & 3; int k0_ = (t_) << 5; \
    gload16(gA0 + k0_, dA + s_ * 8192); \
    gload16(gA1 + k0_, dA + s_ * 8192 + 4096); }
#define STAGE_B(t_) { int s_ = (t_) & 3; int k0_ = (t_) << 5; \
    gload16(gB0 + k0_, dB + s_ * 8192); \
    gload16(gB1 + k0_, dB + s_ * 8192 + 4096); }

  // prologue: stage tiles 0,1,2; confirm tile 0 (8 newer loads stay in flight)
  STAGE_A(0); STAGE_B(0);
  STAGE_A(1); STAGE_B(1);
  STAGE_A(2); STAGE_B(2);
  VMCNT(8);
  __builtin_amdgcn_s_barrier();

  for (int t = 0; t < NT; ++t) {
    const int sb = (t & 3) * 16384;
    // stage tile t+3 (slot (t+3)&3: distinct from t, t+1, t+2 — no reader)
    if (t + 3 < NT) { STAGE_A(t + 3); STAGE_B(t + 3); }
    // read all fragments of tile t (slot confirmed landed + barrier-sync'd)
    short8_t af[8], bf[4];
#pragma unroll
    for (int mi = 0; mi < 8; ++mi)
      af[mi] = *(const short8_t*)(ldsb + sb + aoff + mi * 1024);
#pragma unroll
    for (int nj = 0; nj < 4; ++nj)
      bf[nj] = *(const short8_t*)(ldsb + sb + boff + nj * 1024);
    // confirm stage(t+1) before the barrier that releases tile t+1's reads
    if (t < NT - 3) { VMCNT(8); }
    else if (t == NT - 3) { VMCNT(4); }
    else if (t == NT - 2) { VMCNT(0); }
    __builtin_amdgcn_s_barrier();
    asm volatile("s_waitcnt lgkmcnt(0)" ::: "memory");
    __builtin_amdgcn_sched_barrier(0);
    __builtin_amdgcn_s_setprio(1);
#pragma unroll
    for (int mi = 0; mi < 8; ++mi)
#pragma unroll
      for (int nj = 0; nj < 4; ++nj)
        acc[mi][nj] = mfma16(af[mi], bf[nj], acc[mi][nj]);
    __builtin_amdgcn_s_setprio(0);
    __builtin_amdgcn_s_barrier();
  }
#undef STAGE_A
#undef STAGE_B

  // ---------- epilogue ----------
#pragma unroll
  for (int mi = 0; mi < 8; ++mi) {
#pragma unroll
    for (int nj = 0; nj < 4; ++nj) {
      if (MODE == 2) {
        int row0 = m0 + wm * 128 + mi * 16 + lg * 4;
        int col = n0 + wn * 64 + nj * 16 + ln;
        us4_t pk;
#pragma unroll
        for (int r = 0; r < 4; ++r) pk[r] = f2b(acc[mi][nj][r]);
        *(us4_t*)((unsigned short*)Cout +
                  ((size_t)((row0 >> 11) * 1024 + col)) * 2048 + (row0 & 2047)) = pk;
      } else {
#pragma unroll
        for (int r = 0; r < 4; ++r) {
          int row = m0 + wm * 128 + mi * 16 + lg * 4 + r;
          int col = n0 + wn * 64 + nj * 16 + ln;
          if (MODE == 1)
            ((unsigned short*)Cout)[(size_t)row * ldc + col] = f2b(acc[mi][nj][r]);
          else
            ((float*)Cout)[(size_t)row * ldc + col] = acc[mi][nj][r];
        }
      }
    }
  }
}

// QKV: grid (24, 16). ct<16 -> Q, 16..19 -> K, 20..23 -> V(transposed store).
__global__ __launch_bounds__(512, 1) void gemm_qkv_kernel(
    const unsigned short* __restrict__ xb, const unsigned short* __restrict__ wqb,
    const unsigned short* __restrict__ wkb, const unsigned short* __restrict__ wvb,
    unsigned short* __restrict__ xq, unsigned short* __restrict__ xk,
    unsigned short* __restrict__ xvT) {
  __shared__ __align__(16) unsigned short lds[65536];  // 128 KiB, shared by all modes
  int ct = blockIdx.x, mt = blockIdx.y;
  if (ct < 16)      gemm256_core<1>(lds, xb, wqb, xq, mt * 256, ct * 256, 4096, 4096);
  else if (ct < 20) gemm256_core<1>(lds, xb, wkb, xk, mt * 256, (ct - 16) * 256, 4096, 1024);
  else              gemm256_core<2>(lds, xb, wvb, xvT, mt * 256, (ct - 20) * 256, 4096, 0);
}

__global__ __launch_bounds__(512, 1) void gemm_o_kernel(
    const unsigned short* __restrict__ ao, const unsigned short* __restrict__ wob,
    float* __restrict__ out) {
  __shared__ __align__(16) unsigned short lds[65536];
  gemm256_core<0>(lds, ao, wob, out, blockIdx.y * 256, blockIdx.x * 256, 4096, 4096);
}

// ---------------- RoPE ----------------
template <int NH>
__global__ void rope_kernel(unsigned short* __restrict__ p, const float* __restrict__ fr,
                            int nchunks) {
  for (int c = blockIdx.x * blockDim.x + threadIdx.x; c < nchunks;
       c += gridDim.x * blockDim.x) {
    size_t e = (size_t)c * 8;
    int f0 = (c & 15) * 4;
    int rest = (int)(e >> 7);
    int s = (rest / NH) & 2047;
    unsigned short* ptr = p + e;
    short8_t v = *(short8_t*)ptr;
    const float* cosp = fr + (size_t)s * 64 + f0;
    const float* sinp = cosp + 131072;
#pragma unroll
    for (int j = 0; j < 4; ++j) {
      float re = b2f((unsigned short)v[2 * j]);
      float im = b2f((unsigned short)v[2 * j + 1]);
      float cc = cosp[j], ss = sinp[j];
      v[2 * j]     = (short)f2b(re * cc - im * ss);
      v[2 * j + 1] = (short)f2b(re * ss + im * cc);
    }
    *(short8_t*)ptr = v;
  }
}

// ---------------- flash attention (Round-6 verified): 8 waves x 32 q-rows, 32x32 MFMA ----------------
__global__ __launch_bounds__(512, 2) void attn_kernel(
    const unsigned short* __restrict__ xq, const unsigned short* __restrict__ xk,
    const unsigned short* __restrict__ xvT, unsigned short* __restrict__ ao) {
  __shared__ __align__(16) unsigned char smem[56320];
  const int tid = threadIdx.x;
  const int wq = tid >> 6, lane = tid & 63;
  const int q31 = lane & 31, hi = lane >> 5;
  const int bx = 7 - (int)blockIdx.x;         // LPT: heaviest first
  const int h = blockIdx.y, b = blockIdx.z;
  const int hkv = h >> 2;
  const int q0 = bx * 256;
  const int a0 = q0 + wq * 32;
  const int ktmax_w = a0 >> 6;
  const int NT = bx * 4 + 4;

  const unsigned short* kbase = xk + ((size_t)(b * 2048) * 8 + hkv) * 128;
  const unsigned short* vtg = xvT + (size_t)(b * 1024 + hkv * 128) * 2048;

  const unsigned short* qrow = xq + ((size_t)(b * 2048 + a0 + q31) * 32 + h) * 128;
  short8_t qf[8];
#pragma unroll
  for (int st = 0; st < 8; ++st) qf[st] = *(const short8_t*)(qrow + st * 16 + hi * 8);

  const int c0 = tid, c1 = tid + 512;
  const int kg0 = (c0 >> 4) * 1024 + (c0 & 15) * 8;
  const int kg1 = (c1 >> 4) * 1024 + (c1 & 15) * 8;
  const int ka0 = (c0 >> 4) * 256 + (((c0 & 15) ^ ((c0 >> 4) & 7)) << 4);
  const int ka1 = (c1 >> 4) * 256 + (((c1 & 15) ^ ((c1 >> 4) & 7)) << 4);
  const int d0 = tid >> 3, kb0 = tid & 7, d1v = d0 + 64;
  const int vg0 = d0 * 2048 + kb0 * 8, vg1 = d1v * 2048 + kb0 * 8;
  const int va0 = d0 * 72 + kb0 * 8, va1 = d1v * 72 + kb0 * 8;

  unsigned short* Kb = (unsigned short*)(smem);
  unsigned short* VT = (unsigned short*)(smem + 16384);
  unsigned short* pp = (unsigned short*)(smem + 34816) + wq * 1280;
  unsigned short* prow = pp + q31 * 40;
  float* cl = (float*)(smem + 55296) + wq * 32;

  f32x16 o[4] = {};
  float m_run = -1e30f, l_run = 0.f;

  short8_t kr0 = *(const short8_t*)(kbase + kg0);
  short8_t kr1 = *(const short8_t*)(kbase + kg1);
  short8_t vr0 = *(const short8_t*)(vtg + vg0);
  short8_t vr1 = *(const short8_t*)(vtg + vg1);

  for (int kt = 0; kt < NT; ++kt) {
    *(short8_t*)((unsigned char*)Kb + ka0) = kr0;
    *(short8_t*)((unsigned char*)Kb + ka1) = kr1;
    *(short8_t*)(VT + va0) = vr0;
    *(short8_t*)(VT + va1) = vr1;
    __syncthreads();
    if (kt + 1 < NT) {
      const unsigned short* kg = kbase + (size_t)(kt + 1) * 65536;
      kr0 = *(const short8_t*)(kg + kg0);
      kr1 = *(const short8_t*)(kg + kg1);
      vr0 = *(const short8_t*)(vtg + vg0 + (kt + 1) * 64);
      vr1 = *(const short8_t*)(vtg + vg1 + (kt + 1) * 64);
    }

    if (kt <= ktmax_w) {
      const int r7 = (q31 & 7) << 4;
      f32x16 p0 = {}, p1 = {};
      __builtin_amdgcn_s_setprio(1);
#pragma unroll
      for (int st = 0; st < 8; ++st) {
        int cb = (((st * 2 + hi) << 4)) ^ r7;
        short8_t k0 = *(const short8_t*)((const unsigned char*)Kb + q31 * 256 + cb);
        short8_t k1 = *(const short8_t*)((const unsigned char*)Kb + (q31 + 32) * 256 + cb);
        p0 = mfma32(k0, qf[st], p0);
        p1 = mfma32(k1, qf[st], p1);
      }
      __builtin_amdgcn_s_setprio(0);

      if (kt == ktmax_w) {
        const int q = a0 + q31;
#pragma unroll
        for (int r = 0; r < 16; ++r) {
          int crow = (r & 3) + 8 * (r >> 2) + 4 * hi;
          int kgl = kt * 64 + crow;
          if (kgl > q) p0[r] = -1e30f;
          if (kgl + 32 > q) p1[r] = -1e30f;
        }
      }
      float mx = -1e30f;
#pragma unroll
      for (int r = 0; r < 16; ++r) mx = fmaxf(mx, fmaxf(p0[r], p1[r]));
      mx = fmaxf(mx, __shfl_xor(mx, 32));
      float mnew = fmaxf(m_run, mx);
      float corr = exp2f((m_run - mnew) * CEXP);
      m_run = mnew;
      float sum = 0.f;
#pragma unroll
      for (int r = 0; r < 16; ++r) {
        p0[r] = exp2f((p0[r] - mnew) * CEXP);
        p1[r] = exp2f((p1[r] - mnew) * CEXP);
        sum += p0[r] + p1[r];
      }
      sum += __shfl_xor(sum, 32);
      l_run = l_run * corr + sum;

      cl[q31] = corr;
      f32x4 cv0 = *(const f32x4*)(cl + hi * 4);
      f32x4 cv1 = *(const f32x4*)(cl + 8 + hi * 4);
      f32x4 cv2 = *(const f32x4*)(cl + 16 + hi * 4);
      f32x4 cv3 = *(const f32x4*)(cl + 24 + hi * 4);
#pragma unroll
      for (int db = 0; db < 4; ++db) {
#pragma unroll
        for (int r = 0; r < 4; ++r) {
          o[db][r]      *= cv0[r];
          o[db][4 + r]  *= cv1[r];
          o[db][8 + r]  *= cv2[r];
          o[db][12 + r] *= cv3[r];
        }
      }

#pragma unroll
      for (int u = 0; u < 4; ++u) {
        int2v w;
        w[0] = (int)((unsigned)f2b(p0[4 * u]) | ((unsigned)f2b(p0[4 * u + 1]) << 16));
        w[1] = (int)((unsigned)f2b(p0[4 * u + 2]) | ((unsigned)f2b(p0[4 * u + 3]) << 16));
        *(int2v*)(prow + u * 8 + hi * 4) = w;
      }
      {
        short8_t pa0 = *(const short8_t*)(prow + hi * 8);
        short8_t pa1 = *(const short8_t*)(prow + 16 + hi * 8);
        __builtin_amdgcn_s_setprio(1);
#pragma unroll
        for (int db = 0; db < 4; ++db) {
          const unsigned short* vtd = VT + (db * 32 + q31) * 72;
          short8_t vf0 = *(const short8_t*)(vtd + hi * 8);
          short8_t vf1 = *(const short8_t*)(vtd + 16 + hi * 8);
          o[db] = mfma32(pa0, vf0, o[db]);
          o[db] = mfma32(pa1, vf1, o[db]);
        }
        __builtin_amdgcn_s_setprio(0);
      }
#pragma unroll
      for (int u = 0; u < 4; ++u) {
        int2v w;
        w[0] = (int)((unsigned)f2b(p1[4 * u]) | ((unsigned)f2b(p1[4 * u + 1]) << 16));
        w[1] = (int)((unsigned)f2b(p1[4 * u + 2]) | ((unsigned)f2b(p1[4 * u + 3]) << 16));
        *(int2v*)(prow + u * 8 + hi * 4) = w;
      }
      {
        short8_t pa2 = *(const short8_t*)(prow + hi * 8);
        short8_t pa3 = *(const short8_t*)(prow + 16 + hi * 8);
        __builtin_amdgcn_s_setprio(1);
#pragma unroll
        for (int db = 0; db < 4; ++db) {
          const unsigned short* vtd = VT + (db * 32 + q31) * 72;
          short8_t vf2 = *(const short8_t*)(vtd + 32 + hi * 8);
          short8_t vf3 = *(const short8_t*)(vtd + 48 + hi * 8);
          o[db] = mfma32(pa2, vf2, o[db]);
          o[db] = mfma32(pa3, vf3, o[db]);
        }
        __builtin_amdgcn_s_setprio(0);
      }
    }
    __syncthreads();
  }

  cl[q31] = l_run;
  f32x4 lv0 = *(const f32x4*)(cl + hi * 4);
  f32x4 lv1 = *(const f32x4*)(cl + 8 + hi * 4);
  f32x4 lv2 = *(const f32x4*)(cl + 16 + hi * 4);
  f32x4 lv3 = *(const f32x4*)(cl + 24 + hi * 4);
  f32x4 iv0, iv1, iv2, iv3;
#pragma unroll
  for (int r = 0; r < 4; ++r) {
    iv0[r] = 1.0f / lv0[r]; iv1[r] = 1.0f / lv1[r];
    iv2[r] = 1.0f / lv2[r]; iv3[r] = 1.0f / lv3[r];
  }
  unsigned short* ob = ao + ((size_t)(b * 2048 + a0) * 32 + h) * 128;
#pragma unroll
  for (int db = 0; db < 4; ++db) {
#pragma unroll
    for (int r = 0; r < 16; ++r) {
      int crow = (r & 3) + 8 * (r >> 2) + 4 * hi;
      float iv = (r < 4) ? iv0[r & 3] : (r < 8) ? iv1[r & 3] : (r < 12) ? iv2[r & 3] : iv3[r & 3];
      ob[(size_t)crow * 4096 + db * 32 + q31] = f2b(o[db][r] * iv);
    }
  }
}

// ---------------- launch ----------------
extern "C" void kernel_launch(void* const* d_in, const int* in_sizes, int n_in,
                              void* d_out, int out_size, void* d_ws, size_t ws_size,
                              hipStream_t stream) {
  const float* x  = (const float*)d_in[0];
  const float* wq = (const float*)d_in[1];
  const float* wk = (const float*)d_in[2];
  const float* wv = (const float*)d_in[3];
  const float* wo = (const float*)d_in[4];
  const float* fr = (const float*)d_in[7];
  float* out = (float*)d_out;

  char* ws = (char*)d_ws;
  unsigned short* xb  = (unsigned short*)(ws);               // 33.5MB; reused as ao
  unsigned short* wqb = (unsigned short*)(ws + 33554432);    // 33.5MB; reused as wob
  unsigned short* wkb = (unsigned short*)(ws + 67108864);    // 8.4MB
  unsigned short* wvb = (unsigned short*)(ws + 75497472);    // 8.4MB
  unsigned short* xq  = (unsigned short*)(ws + 83886080);    // 33.5MB
  unsigned short* xk  = (unsigned short*)(ws + 117440512);   // 8.4MB
  unsigned short* xvT = (unsigned short*)(ws + 125829120);   // 8.4MB (total 128MiB)
  unsigned short* ao  = xb;
  unsigned short* wob = wqb;

  dim3 blk(256);
  cvt_kernel<<<dim3(1024), blk, 0, stream>>>(x,  xb,  16777216 / 4);
  cvt_kernel<<<dim3(1024), blk, 0, stream>>>(wq, wqb, 16777216 / 4);
  cvt_kernel<<<dim3(512),  blk, 0, stream>>>(wk, wkb, 4194304 / 4);
  cvt_kernel<<<dim3(512),  blk, 0, stream>>>(wv, wvb, 4194304 / 4);

  gemm_qkv_kernel<<<dim3(24, 16), dim3(512), 0, stream>>>(xb, wqb, wkb, wvb, xq, xk, xvT);

  rope_kernel<32><<<dim3(2048), blk, 0, stream>>>(xq, fr, 2097152);
  rope_kernel<8><<<dim3(512),  blk, 0, stream>>>(xk, fr, 524288);

  cvt_kernel<<<dim3(1024), blk, 0, stream>>>(wo, wob, 16777216 / 4);

  attn_kernel<<<dim3(8, 32, 2), dim3(512), 0, stream>>>(xq, xk, xvT, ao);

  gemm_o_kernel<<<dim3(16, 16), dim3(512), 0, stream>>>(ao, wob, out);
}